// Round 13
// baseline (293.674 us; speedup 1.0000x reference)
//
#include <hip/hip_runtime.h>

#define N_  384
#define C_  128
#define NN_ (N_*N_)

typedef __bf16 bf16x8 __attribute__((ext_vector_type(8)));
typedef float  floatx4 __attribute__((ext_vector_type(4)));

__device__ inline unsigned short f2bf(float f) {
    __bf16 h = (__bf16)f;
    return __builtin_bit_cast(unsigned short, h);
}

// ---------------------------------------------------------------------------
// prep: one-time weight transpose/scale + bias folding. (proven round 1/3)
// ---------------------------------------------------------------------------
__global__ void prep(
    const float* __restrict__ Wl, const float* __restrict__ Wr,
    const float* __restrict__ Wg, const float* __restrict__ We,
    const float* __restrict__ gl, const float* __restrict__ bl,
    const float* __restrict__ gr, const float* __restrict__ br,
    const float* __restrict__ bsl, const float* __restrict__ bse,
    const float* __restrict__ bsr,
    __bf16* __restrict__ WtL, __bf16* __restrict__ WtE,
    __bf16* __restrict__ WtR, __bf16* __restrict__ WtG,
    float* __restrict__ cL, float* __restrict__ cR,
    float* __restrict__ sEw, float* __restrict__ sGw)
{
    const int b = blockIdx.x, t = threadIdx.x;
    if (b < 4) {
        const float* W  = (b==0) ? Wl  : (b==1) ? We  : (b==2) ? Wr  : Wg;
        __bf16*      Wt = (b==0) ? WtL : (b==1) ? WtE : (b==2) ? WtR : WtG;
        float scale = (b==0) ? gl[t] : (b==2) ? gr[t] : 1.f;
        for (int h = 0; h < C_; ++h)
            Wt[(size_t)h*C_ + t] = (__bf16)(W[(size_t)t*C_ + h] * scale);
    } else {
        float aL = 0.f, aR = 0.f, aE = 0.f, aG = 0.f;
        for (int c = 0; c < C_; ++c) {
            aL += bl[c] * Wl[(size_t)c*C_ + t];
            aR += br[c] * Wr[(size_t)c*C_ + t];
            aE += We[(size_t)c*C_ + t];
            aG += Wg[(size_t)c*C_ + t];
        }
        cL[t]  = aL + bsl[t] + bse[t];
        cR[t]  = aR + bsr[t];
        sEw[t] = aE;
        sGw[t] = aG;
    }
}

// ---------------------------------------------------------------------------
// p_proj v13: r12-proven body, with the 32KB sW4 split into a 16KB
// sW2[2][32][128] staged TWICE per half ({L,E} then {R,G}). All index math,
// epilogue, and stores byte-identical to r12. LDS 47.1KB -> 30.7KB =>
// 5 blocks/CU (occupancy was the measured binding constraint: all pipes
// <30% at 2.2 waves/SIMD). Accumulators stay in registers across stages;
// no register arrays live across barriers (r10 spill trap avoided).
// ---------------------------------------------------------------------------
__global__ __launch_bounds__(256) void p_proj(
    const float* __restrict__ pair,
    const __bf16* __restrict__ WtL, const __bf16* __restrict__ WtE,
    const __bf16* __restrict__ WtR, const __bf16* __restrict__ WtG,
    const float* __restrict__ cL, const float* __restrict__ cR,
    const float* __restrict__ sEw, const float* __restrict__ sGw,
    const float* __restrict__ bsg,
    int h0, int nh,
    __bf16* __restrict__ leftC, __bf16* __restrict__ rightC,
    __bf16* __restrict__ gateC)
{
    __shared__ __align__(16) __bf16 sW2[2][32][128];
    __shared__ __align__(16) __bf16 sT3[3][32][72];
    __shared__ float sM[64], sIv[64];

    const int t = threadIdx.x;
    const int rid0 = blockIdx.x * 64;
    const int lane = t & 63, w = t >> 6;
    const int l15 = lane & 15, quad = lane >> 4;
    const int shh = t >> 3, sc8 = t & 7;   // staging coords

    // ---- per-lane load of A-fragment columns + in-register LN ----
    bf16x8 yf[4];
    {
        const int myrow = w*16 + l15;
        const float* prow = pair + (size_t)(rid0 + myrow)*C_;
        float4 xa[4], xb[4];
        float s = 0.f, sq = 0.f;
        #pragma unroll
        for (int ks = 0; ks < 4; ++ks) {
            xa[ks] = *(const float4*)(prow + ks*32 + quad*8);
            xb[ks] = *(const float4*)(prow + ks*32 + quad*8 + 4);
            s  += xa[ks].x + xa[ks].y + xa[ks].z + xa[ks].w
                + xb[ks].x + xb[ks].y + xb[ks].z + xb[ks].w;
            sq += xa[ks].x*xa[ks].x + xa[ks].y*xa[ks].y
                + xa[ks].z*xa[ks].z + xa[ks].w*xa[ks].w
                + xb[ks].x*xb[ks].x + xb[ks].y*xb[ks].y
                + xb[ks].z*xb[ks].z + xb[ks].w*xb[ks].w;
        }
        // reduce across the 4 quads holding this row (xor lane 16, 32)
        s  += __shfl_xor(s, 16);  s  += __shfl_xor(s, 32);
        sq += __shfl_xor(sq, 16); sq += __shfl_xor(sq, 32);
        float m  = s * (1.f/128.f);
        float v  = sq * (1.f/128.f) - m*m;
        float rs = rsqrtf(v + 1e-5f);
        if (quad == 0) { sM[myrow] = m; sIv[myrow] = 1.f / rs; }
        #pragma unroll
        for (int ks = 0; ks < 4; ++ks) {
            yf[ks][0] = (__bf16)((xa[ks].x - m)*rs);
            yf[ks][1] = (__bf16)((xa[ks].y - m)*rs);
            yf[ks][2] = (__bf16)((xa[ks].z - m)*rs);
            yf[ks][3] = (__bf16)((xa[ks].w - m)*rs);
            yf[ks][4] = (__bf16)((xb[ks].x - m)*rs);
            yf[ks][5] = (__bf16)((xb[ks].y - m)*rs);
            yf[ks][6] = (__bf16)((xb[ks].z - m)*rs);
            yf[ks][7] = (__bf16)((xb[ks].w - m)*rs);
        }
    }

    for (int half = 0; half < nh; ++half) {
        const int hb = h0 + half*32;

        floatx4 aL[2] = {}, aE[2] = {}, aR[2] = {}, aG[2] = {};

        // ==== stage 1: {WtL, WtE} -> sW2, MFMA aL/aE ====
        {
            const __bf16* s0 = WtL + (size_t)(hb + shh)*C_;
            const __bf16* s1 = WtE + (size_t)(hb + shh)*C_;
            #pragma unroll
            for (int rep = 0; rep < 2; ++rep) {
                int cc = sc8 + rep*8;
                *(uint4*)&sW2[0][shh][((cc ^ (shh & 7)) << 3)] =
                    *(const uint4*)(s0 + cc*8);
                *(uint4*)&sW2[1][shh][((cc ^ (shh & 7)) << 3)] =
                    *(const uint4*)(s1 + cc*8);
            }
        }
        __syncthreads();   // sW2{L,E} visible (and sM/sIv on half 0)
        #pragma unroll
        for (int ks = 0; ks < 4; ++ks) {
            const int cs = ((ks*4 + quad) ^ (l15 & 7)) << 3;
            const bf16x8 af = yf[ks];
            #pragma unroll
            for (int nt = 0; nt < 2; ++nt) {
                const int hr = nt*16 + l15;
                aL[nt] = __builtin_amdgcn_mfma_f32_16x16x32_bf16(
                    af, *(const bf16x8*)&sW2[0][hr][cs], aL[nt], 0, 0, 0);
                aE[nt] = __builtin_amdgcn_mfma_f32_16x16x32_bf16(
                    af, *(const bf16x8*)&sW2[1][hr][cs], aE[nt], 0, 0, 0);
            }
        }
        __syncthreads();   // sW2{L,E} consumed

        // ==== stage 2: {WtR, WtG} -> sW2, MFMA aR/aG ====
        {
            const __bf16* s0 = WtR + (size_t)(hb + shh)*C_;
            const __bf16* s1 = WtG + (size_t)(hb + shh)*C_;
            #pragma unroll
            for (int rep = 0; rep < 2; ++rep) {
                int cc = sc8 + rep*8;
                *(uint4*)&sW2[0][shh][((cc ^ (shh & 7)) << 3)] =
                    *(const uint4*)(s0 + cc*8);
                *(uint4*)&sW2[1][shh][((cc ^ (shh & 7)) << 3)] =
                    *(const uint4*)(s1 + cc*8);
            }
        }
        __syncthreads();   // sW2{R,G} visible
        #pragma unroll
        for (int ks = 0; ks < 4; ++ks) {
            const int cs = ((ks*4 + quad) ^ (l15 & 7)) << 3;
            const bf16x8 af = yf[ks];
            #pragma unroll
            for (int nt = 0; nt < 2; ++nt) {
                const int hr = nt*16 + l15;
                aR[nt] = __builtin_amdgcn_mfma_f32_16x16x32_bf16(
                    af, *(const bf16x8*)&sW2[0][hr][cs], aR[nt], 0, 0, 0);
                aG[nt] = __builtin_amdgcn_mfma_f32_16x16x32_bf16(
                    af, *(const bf16x8*)&sW2[1][hr][cs], aG[nt], 0, 0, 0);
            }
        }

        // ---- epilogue (r12-proven): write sT3, ONE barrier, 3 stores ----
        #pragma unroll
        for (int nt = 0; nt < 2; ++nt) {
            const int hl_ = nt*16 + l15;
            const float se = sEw[hb + hl_], clv = cL[hb + hl_];
            const float crv = cR[hb + hl_];
            const float sg_ = sGw[hb + hl_], bg = bsg[hb + hl_];
            #pragma unroll
            for (int reg = 0; reg < 4; ++reg) {
                const int rr = w*16 + quad*4 + reg;
                sT3[0][hl_][rr] = (__bf16)(aL[nt][reg] + sIv[rr]*aE[nt][reg]
                                           + sM[rr]*se + clv);
                sT3[1][hl_][rr] = (__bf16)(aR[nt][reg] + crv);
                float z = sIv[rr]*aG[nt][reg] + sM[rr]*sg_ + bg;
                sT3[2][hl_][rr] = (__bf16)(1.f / (1.f + __expf(-z)));
            }
        }
        __syncthreads();   // sT3 ready; sW2 reads complete
        {
            const size_t off = (size_t)(half*32 + shh)*NN_ + rid0 + sc8*8;
            *(uint4*)(leftC  + off) = *(const uint4*)&sT3[0][shh][sc8*8];
            *(uint4*)(rightC + off) = *(const uint4*)&sT3[1][shh][sc8*8];
            *(uint4*)(gateC  + off) = *(const uint4*)&sT3[2][shh][sc8*8];
        }
        if (half + 1 < nh) __syncthreads();   // guard sW2/sT3 restage
    }
}

// ---------------------------------------------------------------------------
// t_right: IN-PLACE transpose of planes [384][384]: [k][j] -> [j][k].
// (proven round 3; plane count set purely by grid size)
// ---------------------------------------------------------------------------
__global__ __launch_bounds__(256) void t_right(__bf16* __restrict__ p)
{
    __shared__ __align__(16) __bf16 tA[64][72];
    __shared__ __align__(16) __bf16 tB[64][72];
    const int plane = blockIdx.x / 21;
    int rem = blockIdx.x % 21, ri = 0;
    while (rem >= 6 - ri) { rem -= 6 - ri; ++ri; }
    const int ci = ri + rem;
    __bf16* base = p + (size_t)plane * NN_;
    const int t = threadIdx.x;
    const int r = t >> 2, c0 = (t & 3) * 16;

    {
        const __bf16* srcA = base + (size_t)(ri*64 + r)*N_ + ci*64 + c0;
        *(uint4*)&tA[r][c0]   = *(const uint4*)(srcA);
        *(uint4*)&tA[r][c0+8] = *(const uint4*)(srcA + 8);
        if (ri != ci) {
            const __bf16* srcB = base + (size_t)(ci*64 + r)*N_ + ri*64 + c0;
            *(uint4*)&tB[r][c0]   = *(const uint4*)(srcB);
            *(uint4*)&tB[r][c0+8] = *(const uint4*)(srcB + 8);
        }
    }
    __syncthreads();
    {
        union { unsigned short us[8]; uint4 v; } o0, o1;
        #pragma unroll
        for (int u = 0; u < 8; ++u) {
            o0.us[u] = __builtin_bit_cast(unsigned short, tA[c0+u][r]);
            o1.us[u] = __builtin_bit_cast(unsigned short, tA[c0+8+u][r]);
        }
        __bf16* dA = base + (size_t)(ci*64 + r)*N_ + ri*64 + c0;
        *(uint4*)(dA)     = o0.v;
        *(uint4*)(dA + 8) = o1.v;
        if (ri != ci) {
            union { unsigned short us[8]; uint4 v; } p0, p1;
            #pragma unroll
            for (int u = 0; u < 8; ++u) {
                p0.us[u] = __builtin_bit_cast(unsigned short, tB[c0+u][r]);
                p1.us[u] = __builtin_bit_cast(unsigned short, tB[c0+8+u][r]);
            }
            __bf16* dB = base + (size_t)(ri*64 + r)*N_ + ci*64 + c0;
            *(uint4*)(dB)     = p0.v;
            *(uint4*)(dB + 8) = p1.v;
        }
    }
}

// ---------------------------------------------------------------------------
// k_einsum: VERBATIM round-9/12 proven version (r3 indexing + sGate union +
// XCD swizzle with gridDim-derived stride).
// ---------------------------------------------------------------------------
__global__ __launch_bounds__(256) void k_einsum(
    const __bf16* __restrict__ leftC, const __bf16* __restrict__ rightC,
    const __bf16* __restrict__ gate, __bf16* __restrict__ outG)
{
    __shared__ __align__(16) unsigned char smem[128*136*2];
    __bf16 (*sA)[40]    = (__bf16(*)[40])smem;
    __bf16 (*sB)[40]    = (__bf16(*)[40])(smem + 128*40*2);
    __bf16 (*sGate)[136] = (__bf16(*)[136])smem;

    // XCD swizzle: blocks sharing one h-plane co-locate on one XCD's L2.
    const int cpx = gridDim.x >> 3;
    const int bid = (blockIdx.x & 7) * cpx + (blockIdx.x >> 3);
    const int hl = bid / 9, t9 = bid % 9;
    const int ti = (t9 / 3) * 128, tj = (t9 % 3) * 128;
    const int tid = threadIdx.x, lane = tid & 63, w = tid >> 6;
    const int l15 = lane & 15, quad = lane >> 4;
    const size_t hNN = (size_t)hl * NN_;

    const int ar = (lane >> 2);
    const int ac = (lane & 3) * 8;
    const __bf16* gA = leftC  + hNN + (size_t)ti * N_;
    const __bf16* gB = rightC + hNN + (size_t)tj * N_;

    floatx4 acc[4][4] = {};

    for (int ks = 0; ks < 12; ++ks) {
        const int kc = ks * 32;
        uint4 va[2], vb[2];
        #pragma unroll
        for (int it = 0; it < 2; ++it) {
            int row = w*32 + it*16 + ar;
            va[it] = *(const uint4*)(gA + (size_t)row*N_ + kc + ac);
            vb[it] = *(const uint4*)(gB + (size_t)row*N_ + kc + ac);
        }
        #pragma unroll
        for (int it = 0; it < 2; ++it) {
            int row = w*32 + it*16 + ar;
            *(uint4*)&sA[row][ac] = va[it];
            *(uint4*)&sB[row][ac] = vb[it];
        }
        __syncthreads();
        bf16x8 af[4], bfr[4];
        #pragma unroll
        for (int mt = 0; mt < 4; ++mt)
            af[mt] = *(const bf16x8*)&sA[(w&1)*64 + mt*16 + l15][quad*8];
        #pragma unroll
        for (int nt = 0; nt < 4; ++nt)
            bfr[nt] = *(const bf16x8*)&sB[(w>>1)*64 + nt*16 + l15][quad*8];
        #pragma unroll
        for (int mt = 0; mt < 4; ++mt)
            #pragma unroll
            for (int nt = 0; nt < 4; ++nt)
                acc[mt][nt] = __builtin_amdgcn_mfma_f32_16x16x32_bf16(
                    af[mt], bfr[nt], acc[mt][nt], 0, 0, 0);
        __syncthreads();
    }

    // stage gate tile gate[i][j] into the SAME LDS (sA/sB dead after barrier)
    #pragma unroll
    for (int it = 0; it < 8; ++it) {
        int cid = it*256 + tid;
        int ri = cid >> 4, c8 = cid & 15;
        *(uint4*)&sGate[ri][c8*8] =
            *(const uint4*)(gate + hNN + (size_t)(ti + ri)*N_ + tj + c8*8);
    }
    __syncthreads();

    const int ib = (w & 1) * 64, jbw = (w >> 1) * 64;
    #pragma unroll
    for (int mt = 0; mt < 4; ++mt) {
        const int i_base = ib + mt*16 + quad*4;
        #pragma unroll
        for (int nt = 0; nt < 4; ++nt) {
            const int j_loc = jbw + nt*16 + l15;
            union { unsigned short us[4]; uint2 v; } p;
            #pragma unroll
            for (int rr = 0; rr < 4; ++rr) {
                float g = (float)sGate[i_base + rr][j_loc];
                p.us[rr] = f2bf(acc[mt][nt][rr] * g);
            }
            *(uint2*)(outG + hNN + (size_t)(tj + j_loc)*N_ + ti + i_base) = p.v;
        }
    }
}

// ---------------------------------------------------------------------------
// p_out: PROVEN round-1/3 code, verbatim.
// ---------------------------------------------------------------------------
__global__ __launch_bounds__(256) void p_out(
    const __bf16* __restrict__ outG, const float* __restrict__ Wo,
    const float* __restrict__ bso,  const float* __restrict__ pair,
    const float* __restrict__ go,   const float* __restrict__ bo,
    float* __restrict__ out)
{
    __shared__ __align__(16) __bf16 sOh[64][128];
    __shared__ __align__(16) __bf16 sWo[128][128];

    const int t = threadIdx.x;
    const int j  = blockIdx.x / 6;
    const int i0 = (blockIdx.x % 6) * 64;
    const int lane = t & 63, w = t >> 6;
    const int l15 = lane & 15, quad = lane >> 4;

    // stage sOh[i][h] (swizzled) from outG plane layout [h][j][i]
    {
        const int h = t >> 1, ibase = (t & 1) * 32;
        const __bf16* src = outG + (size_t)h*NN_ + (size_t)j*N_ + i0 + ibase;
        #pragma unroll
        for (int u = 0; u < 4; ++u) {
            uint4 vv = *(const uint4*)(src + u*8);
            const unsigned short* pv = (const unsigned short*)&vv;
            #pragma unroll
            for (int k = 0; k < 8; ++k) {
                int i = ibase + u*8 + k;
                sOh[i][(((h >> 3) ^ (i & 7)) << 3) + (h & 7)] =
                    __builtin_bit_cast(__bf16, pv[k]);
            }
        }
    }
    // stage sWo[c][h] = Wo^T (swizzled), Wo stored [h][c] f32
    {
        const int h = t >> 1, cbase = (t & 1) * 64;
        const float* src = Wo + (size_t)h*C_ + cbase;
        #pragma unroll
        for (int u = 0; u < 16; ++u) {
            float4 wv = *(const float4*)(src + u*4);
            const float* wf = (const float*)&wv;
            #pragma unroll
            for (int k = 0; k < 4; ++k) {
                int c = cbase + u*4 + k;
                sWo[c][(((h >> 3) ^ (c & 7)) << 3) + (h & 7)] = (__bf16)wf[k];
            }
        }
    }
    __syncthreads();

    floatx4 acc[8] = {};
    #pragma unroll
    for (int ks = 0; ks < 4; ++ks) {
        const int cs = ((ks*4 + quad) ^ (l15 & 7)) << 3;
        bf16x8 af = *(const bf16x8*)&sOh[w*16 + l15][cs];
        #pragma unroll
        for (int nt = 0; nt < 8; ++nt)
            acc[nt] = __builtin_amdgcn_mfma_f32_16x16x32_bf16(
                af, *(const bf16x8*)&sWo[nt*16 + l15][cs], acc[nt], 0, 0, 0);
    }

    float bsov[8], gov[8], bov[8];
    #pragma unroll
    for (int nt = 0; nt < 8; ++nt) {
        const int c = nt*16 + l15;
        bsov[nt] = bso[c]; gov[nt] = go[c]; bov[nt] = bo[c];
    }

    #pragma unroll
    for (int reg = 0; reg < 4; ++reg) {
        const int i = i0 + w*16 + quad*4 + reg;
        const float* prow = pair + ((size_t)i*N_ + j)*C_;
        float zz[8];
        float ssum = 0.f, ssq = 0.f;
        #pragma unroll
        for (int nt = 0; nt < 8; ++nt) {
            float zv = acc[nt][reg] + bsov[nt] + prow[nt*16 + l15];
            zz[nt] = zv; ssum += zv; ssq += zv*zv;
        }
        #pragma unroll
        for (int d = 1; d < 16; d <<= 1) {
            ssum += __shfl_xor(ssum, d);
            ssq  += __shfl_xor(ssq, d);
        }
        const float mm = ssum * (1.f/128.f);
        const float vv = ssq * (1.f/128.f) - mm*mm;
        const float rr = rsqrtf(vv + 1e-5f);
        float* orow = out + ((size_t)i*N_ + j)*C_;
        #pragma unroll
        for (int nt = 0; nt < 8; ++nt)
            orow[nt*16 + l15] = (zz[nt] - mm)*rr*gov[nt] + bov[nt];
    }
}

// ---------------------------------------------------------------------------
extern "C" void kernel_launch(void* const* d_in, const int* in_sizes, int n_in,
                              void* d_out, int out_size, void* d_ws, size_t ws_size,
                              hipStream_t stream)
{
    const float* pair    = (const float*)d_in[0];
    const float* g_left  = (const float*)d_in[1];
    const float* b_left  = (const float*)d_in[2];
    const float* g_right = (const float*)d_in[3];
    const float* b_right = (const float*)d_in[4];
    const float* g_out   = (const float*)d_in[5];
    const float* b_out   = (const float*)d_in[6];
    const float* W_l     = (const float*)d_in[7];
    const float* bias_l  = (const float*)d_in[8];
    const float* W_r     = (const float*)d_in[9];
    const float* bias_r  = (const float*)d_in[10];
    const float* W_g     = (const float*)d_in[11];
    const float* bias_g  = (const float*)d_in[12];
    const float* W_e     = (const float*)d_in[13];
    const float* bias_e  = (const float*)d_in[14];
    const float* W_o     = (const float*)d_in[15];
    const float* bias_o  = (const float*)d_in[16];

    const size_t PLANES128 = (size_t)128 * NN_;              // elements
    const size_t NEED = PLANES128*2*2 + 65536*2 + 512*4;     // bytes

    if (ws_size >= NEED) {
        // ---- single pass: all 128 h in one round (proven round 9) ----
        __bf16* leftC  = (__bf16*)d_out;
        __bf16* gateC  = leftC + PLANES128;
        __bf16* rightC = (__bf16*)d_ws;
        __bf16* outG   = rightC + PLANES128;
        char* prepBase = (char*)d_ws + PLANES128*2*2;
        __bf16* WtL = (__bf16*)prepBase;
        __bf16* WtE = WtL + 16384;
        __bf16* WtR = WtL + 32768;
        __bf16* WtG = WtL + 49152;
        float*  cL  = (float*)(WtL + 65536);
        float*  cR  = cL + 128;
        float*  sEw = cL + 256;
        float*  sGw = cL + 384;

        prep<<<5, 128, 0, stream>>>(W_l, W_r, W_g, W_e,
                                    g_left, b_left, g_right, b_right,
                                    bias_l, bias_e, bias_r,
                                    WtL, WtE, WtR, WtG, cL, cR, sEw, sGw);
        p_proj<<<NN_/64, 256, 0, stream>>>(pair, WtL, WtE, WtR, WtG,
                                           cL, cR, sEw, sGw, bias_g,
                                           0, 4, leftC, rightC, gateC);
        t_right<<<128*21, 256, 0, stream>>>(rightC);
        k_einsum<<<128*9, 256, 0, stream>>>(leftC, rightC, gateC, outG);
        p_out<<<2304, 256, 0, stream>>>(outG, W_o, bias_o, pair,
                                        g_out, b_out, (float*)d_out);
    } else {
        // ---- fallback: r8-proven two-pass layout ----
        __bf16* outG   = (__bf16*)d_ws;
        __bf16* leftC  = (__bf16*)d_out;
        __bf16* rightC = leftC + (size_t)64*NN_;
        __bf16* gateC  = leftC + (size_t)128*NN_;

        char* prepBase = (char*)d_out + ((size_t)60 << 20);
        __bf16* WtL = (__bf16*)prepBase;
        __bf16* WtE = WtL + 16384;
        __bf16* WtR = WtL + 32768;
        __bf16* WtG = WtL + 49152;
        float*  cL  = (float*)(WtL + 65536);
        float*  cR  = cL + 128;
        float*  sEw = cL + 256;
        float*  sGw = cL + 384;

        prep<<<5, 128, 0, stream>>>(W_l, W_r, W_g, W_e,
                                    g_left, b_left, g_right, b_right,
                                    bias_l, bias_e, bias_r,
                                    WtL, WtE, WtR, WtG, cL, cR, sEw, sGw);

        for (int h0 = 0; h0 < 128; h0 += 64) {
            p_proj<<<NN_/64, 256, 0, stream>>>(pair, WtL, WtE, WtR, WtG,
                                               cL, cR, sEw, sGw, bias_g,
                                               h0, 2, leftC, rightC, gateC);
            t_right<<<64*21, 256, 0, stream>>>(rightC);
            k_einsum<<<64*9, 256, 0, stream>>>(leftC, rightC, gateC,
                                               outG + (size_t)h0*NN_);
        }
        p_out<<<2304, 256, 0, stream>>>(outG, W_o, bias_o, pair,
                                        g_out, b_out, (float*)d_out);
    }
}

// Round 15
// 285.962 us; speedup vs baseline: 1.0270x; 1.0270x over previous
//
#include <hip/hip_runtime.h>

#define N_  384
#define C_  128
#define NN_ (N_*N_)

typedef __bf16 bf16x8 __attribute__((ext_vector_type(8)));
typedef float  floatx4 __attribute__((ext_vector_type(4)));

__device__ inline unsigned short f2bf(float f) {
    __bf16 h = (__bf16)f;
    return __builtin_bit_cast(unsigned short, h);
}

// ---------------------------------------------------------------------------
// prep: one-time weight transpose/scale + bias folding (proven r1/r3), plus
// block 5: WoS = pre-swizzled bf16 image of Wo^T, the exact 32KB LDS
// image p_out's sWo staging used to rebuild per-block. Inverse map verified:
// x = ((h>>3)^(c&7))<<3 | (h&7)  <=>  h = ((x>>3)^(c&7))<<3 | (x&7).
// ---------------------------------------------------------------------------
__global__ void prep(
    const float* __restrict__ Wl, const float* __restrict__ Wr,
    const float* __restrict__ Wg, const float* __restrict__ We,
    const float* __restrict__ Wo,
    const float* __restrict__ gl, const float* __restrict__ bl,
    const float* __restrict__ gr, const float* __restrict__ br,
    const float* __restrict__ bsl, const float* __restrict__ bse,
    const float* __restrict__ bsr,
    __bf16* __restrict__ WtL, __bf16* __restrict__ WtE,
    __bf16* __restrict__ WtR, __bf16* __restrict__ WtG,
    float* __restrict__ cL, float* __restrict__ cR,
    float* __restrict__ sEw, float* __restrict__ sGw,
    __bf16* __restrict__ WoS)
{
    const int b = blockIdx.x, t = threadIdx.x;
    if (b < 4) {
        const float* W  = (b==0) ? Wl  : (b==1) ? We  : (b==2) ? Wr  : Wg;
        __bf16*      Wt = (b==0) ? WtL : (b==1) ? WtE : (b==2) ? WtR : WtG;
        float scale = (b==0) ? gl[t] : (b==2) ? gr[t] : 1.f;
        for (int h = 0; h < C_; ++h)
            Wt[(size_t)h*C_ + t] = (__bf16)(W[(size_t)t*C_ + h] * scale);
    } else if (b == 4) {
        float aL = 0.f, aR = 0.f, aE = 0.f, aG = 0.f;
        for (int c = 0; c < C_; ++c) {
            aL += bl[c] * Wl[(size_t)c*C_ + t];
            aR += br[c] * Wr[(size_t)c*C_ + t];
            aE += We[(size_t)c*C_ + t];
            aG += Wg[(size_t)c*C_ + t];
        }
        cL[t]  = aL + bsl[t] + bse[t];
        cR[t]  = aR + bsr[t];
        sEw[t] = aE;
        sGw[t] = aG;
    } else {
        // WoS[c][x] = (bf16)Wo[h(x,c)][c], the pre-swizzled sWo image (t = c)
        const int c = t;
        for (int x = 0; x < C_; ++x) {
            int h = (((x >> 3) ^ (c & 7)) << 3) + (x & 7);
            WoS[(size_t)c*C_ + x] = (__bf16)Wo[(size_t)h*C_ + c];
        }
    }
}

// ---------------------------------------------------------------------------
// p_proj: VERBATIM round-12 proven version (best measured: 289.7us total).
// r13's sW2 split was occupancy-neutral -> reverted.
// ---------------------------------------------------------------------------
__global__ __launch_bounds__(256) void p_proj(
    const float* __restrict__ pair,
    const __bf16* __restrict__ WtL, const __bf16* __restrict__ WtE,
    const __bf16* __restrict__ WtR, const __bf16* __restrict__ WtG,
    const float* __restrict__ cL, const float* __restrict__ cR,
    const float* __restrict__ sEw, const float* __restrict__ sGw,
    const float* __restrict__ bsg,
    int h0, int nh,
    __bf16* __restrict__ leftC, __bf16* __restrict__ rightC,
    __bf16* __restrict__ gateC)
{
    __shared__ __align__(16) __bf16 sW4[4][32][128];
    __shared__ __align__(16) __bf16 sT3[3][32][72];
    __shared__ float sM[64], sIv[64];

    const int t = threadIdx.x;
    const int rid0 = blockIdx.x * 64;
    const int lane = t & 63, w = t >> 6;
    const int l15 = lane & 15, quad = lane >> 4;

    // ---- per-lane load of A-fragment columns + in-register LN ----
    bf16x8 yf[4];
    {
        const int myrow = w*16 + l15;
        const float* prow = pair + (size_t)(rid0 + myrow)*C_;
        float4 xa[4], xb[4];
        float s = 0.f, sq = 0.f;
        #pragma unroll
        for (int ks = 0; ks < 4; ++ks) {
            xa[ks] = *(const float4*)(prow + ks*32 + quad*8);
            xb[ks] = *(const float4*)(prow + ks*32 + quad*8 + 4);
            s  += xa[ks].x + xa[ks].y + xa[ks].z + xa[ks].w
                + xb[ks].x + xb[ks].y + xb[ks].z + xb[ks].w;
            sq += xa[ks].x*xa[ks].x + xa[ks].y*xa[ks].y
                + xa[ks].z*xa[ks].z + xa[ks].w*xa[ks].w
                + xb[ks].x*xb[ks].x + xb[ks].y*xb[ks].y
                + xb[ks].z*xb[ks].z + xb[ks].w*xb[ks].w;
        }
        // reduce across the 4 quads holding this row (xor lane 16, 32)
        s  += __shfl_xor(s, 16);  s  += __shfl_xor(s, 32);
        sq += __shfl_xor(sq, 16); sq += __shfl_xor(sq, 32);
        float m  = s * (1.f/128.f);
        float v  = sq * (1.f/128.f) - m*m;
        float rs = rsqrtf(v + 1e-5f);
        if (quad == 0) { sM[myrow] = m; sIv[myrow] = 1.f / rs; }
        #pragma unroll
        for (int ks = 0; ks < 4; ++ks) {
            yf[ks][0] = (__bf16)((xa[ks].x - m)*rs);
            yf[ks][1] = (__bf16)((xa[ks].y - m)*rs);
            yf[ks][2] = (__bf16)((xa[ks].z - m)*rs);
            yf[ks][3] = (__bf16)((xa[ks].w - m)*rs);
            yf[ks][4] = (__bf16)((xb[ks].x - m)*rs);
            yf[ks][5] = (__bf16)((xb[ks].y - m)*rs);
            yf[ks][6] = (__bf16)((xb[ks].z - m)*rs);
            yf[ks][7] = (__bf16)((xb[ks].w - m)*rs);
        }
    }

    for (int half = 0; half < nh; ++half) {
        const int hb = h0 + half*32;
        // stage 4 weight tiles [32h][128c], swizzled (already bf16+transposed)
        {
            const int hh = t >> 3, c8 = t & 7;
            const __bf16* srcs[4] = {
                WtL + (size_t)(hb + hh)*C_, WtE + (size_t)(hb + hh)*C_,
                WtR + (size_t)(hb + hh)*C_, WtG + (size_t)(hb + hh)*C_ };
            #pragma unroll
            for (int mat = 0; mat < 4; ++mat) {
                #pragma unroll
                for (int rep = 0; rep < 2; ++rep) {
                    int cc = c8 + rep*8;
                    *(uint4*)&sW4[mat][hh][((cc ^ (hh & 7)) << 3)] =
                        *(const uint4*)(srcs[mat] + cc*8);
                }
            }
        }
        __syncthreads();   // sW4 visible (and sM/sIv on half 0)

        floatx4 aL[2] = {}, aE[2] = {}, aR[2] = {}, aG[2] = {};
        #pragma unroll
        for (int ks = 0; ks < 4; ++ks) {
            const int cs = ((ks*4 + quad) ^ (l15 & 7)) << 3;
            const bf16x8 af = yf[ks];
            #pragma unroll
            for (int nt = 0; nt < 2; ++nt) {
                const int hr = nt*16 + l15;
                aL[nt] = __builtin_amdgcn_mfma_f32_16x16x32_bf16(
                    af, *(const bf16x8*)&sW4[0][hr][cs], aL[nt], 0, 0, 0);
                aE[nt] = __builtin_amdgcn_mfma_f32_16x16x32_bf16(
                    af, *(const bf16x8*)&sW4[1][hr][cs], aE[nt], 0, 0, 0);
                aR[nt] = __builtin_amdgcn_mfma_f32_16x16x32_bf16(
                    af, *(const bf16x8*)&sW4[2][hr][cs], aR[nt], 0, 0, 0);
                aG[nt] = __builtin_amdgcn_mfma_f32_16x16x32_bf16(
                    af, *(const bf16x8*)&sW4[3][hr][cs], aG[nt], 0, 0, 0);
            }
        }

        // ---- epilogue (proven): write sT3, ONE barrier, 3 stores ----
        #pragma unroll
        for (int nt = 0; nt < 2; ++nt) {
            const int hl_ = nt*16 + l15;
            const float se = sEw[hb + hl_], clv = cL[hb + hl_];
            const float crv = cR[hb + hl_];
            const float sg_ = sGw[hb + hl_], bg = bsg[hb + hl_];
            #pragma unroll
            for (int reg = 0; reg < 4; ++reg) {
                const int rr = w*16 + quad*4 + reg;
                sT3[0][hl_][rr] = (__bf16)(aL[nt][reg] + sIv[rr]*aE[nt][reg]
                                           + sM[rr]*se + clv);
                sT3[1][hl_][rr] = (__bf16)(aR[nt][reg] + crv);
                float z = sIv[rr]*aG[nt][reg] + sM[rr]*sg_ + bg;
                sT3[2][hl_][rr] = (__bf16)(1.f / (1.f + __expf(-z)));
            }
        }
        __syncthreads();
        {
            const int hh = t >> 3, sg = t & 7;
            const size_t off = (size_t)(half*32 + hh)*NN_ + rid0 + sg*8;
            *(uint4*)(leftC  + off) = *(const uint4*)&sT3[0][hh][sg*8];
            *(uint4*)(rightC + off) = *(const uint4*)&sT3[1][hh][sg*8];
            *(uint4*)(gateC  + off) = *(const uint4*)&sT3[2][hh][sg*8];
        }
        if (half + 1 < nh) __syncthreads();   // guard sW4/sT3 restage
    }
}

// ---------------------------------------------------------------------------
// t_right: IN-PLACE transpose of planes [384][384]: [k][j] -> [j][k].
// (proven round 3; plane count set purely by grid size)
// ---------------------------------------------------------------------------
__global__ __launch_bounds__(256) void t_right(__bf16* __restrict__ p)
{
    __shared__ __align__(16) __bf16 tA[64][72];
    __shared__ __align__(16) __bf16 tB[64][72];
    const int plane = blockIdx.x / 21;
    int rem = blockIdx.x % 21, ri = 0;
    while (rem >= 6 - ri) { rem -= 6 - ri; ++ri; }
    const int ci = ri + rem;
    __bf16* base = p + (size_t)plane * NN_;
    const int t = threadIdx.x;
    const int r = t >> 2, c0 = (t & 3) * 16;

    {
        const __bf16* srcA = base + (size_t)(ri*64 + r)*N_ + ci*64 + c0;
        *(uint4*)&tA[r][c0]   = *(const uint4*)(srcA);
        *(uint4*)&tA[r][c0+8] = *(const uint4*)(srcA + 8);
        if (ri != ci) {
            const __bf16* srcB = base + (size_t)(ci*64 + r)*N_ + ri*64 + c0;
            *(uint4*)&tB[r][c0]   = *(const uint4*)(srcB);
            *(uint4*)&tB[r][c0+8] = *(const uint4*)(srcB + 8);
        }
    }
    __syncthreads();
    {
        union { unsigned short us[8]; uint4 v; } o0, o1;
        #pragma unroll
        for (int u = 0; u < 8; ++u) {
            o0.us[u] = __builtin_bit_cast(unsigned short, tA[c0+u][r]);
            o1.us[u] = __builtin_bit_cast(unsigned short, tA[c0+8+u][r]);
        }
        __bf16* dA = base + (size_t)(ci*64 + r)*N_ + ri*64 + c0;
        *(uint4*)(dA)     = o0.v;
        *(uint4*)(dA + 8) = o1.v;
        if (ri != ci) {
            union { unsigned short us[8]; uint4 v; } p0, p1;
            #pragma unroll
            for (int u = 0; u < 8; ++u) {
                p0.us[u] = __builtin_bit_cast(unsigned short, tB[c0+u][r]);
                p1.us[u] = __builtin_bit_cast(unsigned short, tB[c0+8+u][r]);
            }
            __bf16* dB = base + (size_t)(ri*64 + r)*N_ + ci*64 + c0;
            *(uint4*)(dB)     = p0.v;
            *(uint4*)(dB + 8) = p1.v;
        }
    }
}

// ---------------------------------------------------------------------------
// k_einsum: VERBATIM round-9/12 proven version.
// ---------------------------------------------------------------------------
__global__ __launch_bounds__(256) void k_einsum(
    const __bf16* __restrict__ leftC, const __bf16* __restrict__ rightC,
    const __bf16* __restrict__ gate, __bf16* __restrict__ outG)
{
    __shared__ __align__(16) unsigned char smem[128*136*2];
    __bf16 (*sA)[40]    = (__bf16(*)[40])smem;
    __bf16 (*sB)[40]    = (__bf16(*)[40])(smem + 128*40*2);
    __bf16 (*sGate)[136] = (__bf16(*)[136])smem;

    // XCD swizzle: blocks sharing one h-plane co-locate on one XCD's L2.
    const int cpx = gridDim.x >> 3;
    const int bid = (blockIdx.x & 7) * cpx + (blockIdx.x >> 3);
    const int hl = bid / 9, t9 = bid % 9;
    const int ti = (t9 / 3) * 128, tj = (t9 % 3) * 128;
    const int tid = threadIdx.x, lane = tid & 63, w = tid >> 6;
    const int l15 = lane & 15, quad = lane >> 4;
    const size_t hNN = (size_t)hl * NN_;

    const int ar = (lane >> 2);
    const int ac = (lane & 3) * 8;
    const __bf16* gA = leftC  + hNN + (size_t)ti * N_;
    const __bf16* gB = rightC + hNN + (size_t)tj * N_;

    floatx4 acc[4][4] = {};

    for (int ks = 0; ks < 12; ++ks) {
        const int kc = ks * 32;
        uint4 va[2], vb[2];
        #pragma unroll
        for (int it = 0; it < 2; ++it) {
            int row = w*32 + it*16 + ar;
            va[it] = *(const uint4*)(gA + (size_t)row*N_ + kc + ac);
            vb[it] = *(const uint4*)(gB + (size_t)row*N_ + kc + ac);
        }
        #pragma unroll
        for (int it = 0; it < 2; ++it) {
            int row = w*32 + it*16 + ar;
            *(uint4*)&sA[row][ac] = va[it];
            *(uint4*)&sB[row][ac] = vb[it];
        }
        __syncthreads();
        bf16x8 af[4], bfr[4];
        #pragma unroll
        for (int mt = 0; mt < 4; ++mt)
            af[mt] = *(const bf16x8*)&sA[(w&1)*64 + mt*16 + l15][quad*8];
        #pragma unroll
        for (int nt = 0; nt < 4; ++nt)
            bfr[nt] = *(const bf16x8*)&sB[(w>>1)*64 + nt*16 + l15][quad*8];
        #pragma unroll
        for (int mt = 0; mt < 4; ++mt)
            #pragma unroll
            for (int nt = 0; nt < 4; ++nt)
                acc[mt][nt] = __builtin_amdgcn_mfma_f32_16x16x32_bf16(
                    af[mt], bfr[nt], acc[mt][nt], 0, 0, 0);
        __syncthreads();
    }

    // stage gate tile gate[i][j] into the SAME LDS (sA/sB dead after barrier)
    #pragma unroll
    for (int it = 0; it < 8; ++it) {
        int cid = it*256 + tid;
        int ri = cid >> 4, c8 = cid & 15;
        *(uint4*)&sGate[ri][c8*8] =
            *(const uint4*)(gate + hNN + (size_t)(ti + ri)*N_ + tj + c8*8);
    }
    __syncthreads();

    const int ib = (w & 1) * 64, jbw = (w >> 1) * 64;
    #pragma unroll
    for (int mt = 0; mt < 4; ++mt) {
        const int i_base = ib + mt*16 + quad*4;
        #pragma unroll
        for (int nt = 0; nt < 4; ++nt) {
            const int j_loc = jbw + nt*16 + l15;
            union { unsigned short us[4]; uint2 v; } p;
            #pragma unroll
            for (int rr = 0; rr < 4; ++rr) {
                float g = (float)sGate[i_base + rr][j_loc];
                p.us[rr] = f2bf(acc[mt][nt][rr] * g);
            }
            *(uint2*)(outG + hNN + (size_t)(tj + j_loc)*N_ + ti + i_base) = p.v;
        }
    }
}

// ---------------------------------------------------------------------------
// p_out: proven r1/r3 body; ONLY change: when WoS != nullptr, sWo is staged
// by direct uint4 copy of the prep-built pre-swizzled image (replaces 16 f32
// loads + 64 scalar converts + 64 scalar LDS scatters per thread).
// ---------------------------------------------------------------------------
__global__ __launch_bounds__(256) void p_out(
    const __bf16* __restrict__ outG, const float* __restrict__ Wo,
    const __bf16* __restrict__ WoS,
    const float* __restrict__ bso,  const float* __restrict__ pair,
    const float* __restrict__ go,   const float* __restrict__ bo,
    float* __restrict__ out)
{
    __shared__ __align__(16) __bf16 sOh[64][128];
    __shared__ __align__(16) __bf16 sWo[128][128];

    const int t = threadIdx.x;
    const int j  = blockIdx.x / 6;
    const int i0 = (blockIdx.x % 6) * 64;
    const int lane = t & 63, w = t >> 6;
    const int l15 = lane & 15, quad = lane >> 4;

    // stage sOh[i][h] (swizzled) from outG plane layout [h][j][i]
    {
        const int h = t >> 1, ibase = (t & 1) * 32;
        const __bf16* src = outG + (size_t)h*NN_ + (size_t)j*N_ + i0 + ibase;
        #pragma unroll
        for (int u = 0; u < 4; ++u) {
            uint4 vv = *(const uint4*)(src + u*8);
            const unsigned short* pv = (const unsigned short*)&vv;
            #pragma unroll
            for (int k = 0; k < 8; ++k) {
                int i = ibase + u*8 + k;
                sOh[i][(((h >> 3) ^ (i & 7)) << 3) + (h & 7)] =
                    __builtin_bit_cast(__bf16, pv[k]);
            }
        }
    }
    // stage sWo: fast path = copy pre-swizzled image; slow path = old build
    if (WoS) {
        const int c = t >> 1, seg = t & 1;
        const __bf16* src = WoS + (size_t)c*C_ + seg*64;
        #pragma unroll
        for (int u = 0; u < 8; ++u)
            *(uint4*)&sWo[c][seg*64 + u*8] = *(const uint4*)(src + u*8);
    } else {
        const int h = t >> 1, cbase = (t & 1) * 64;
        const float* src = Wo + (size_t)h*C_ + cbase;
        #pragma unroll
        for (int u = 0; u < 16; ++u) {
            float4 wv = *(const float4*)(src + u*4);
            const float* wf = (const float*)&wv;
            #pragma unroll
            for (int k = 0; k < 4; ++k) {
                int c = cbase + u*4 + k;
                sWo[c][(((h >> 3) ^ (c & 7)) << 3) + (h & 7)] = (__bf16)wf[k];
            }
        }
    }
    __syncthreads();

    floatx4 acc[8] = {};
    #pragma unroll
    for (int ks = 0; ks < 4; ++ks) {
        const int cs = ((ks*4 + quad) ^ (l15 & 7)) << 3;
        bf16x8 af = *(const bf16x8*)&sOh[w*16 + l15][cs];
        #pragma unroll
        for (int nt = 0; nt < 8; ++nt)
            acc[nt] = __builtin_amdgcn_mfma_f32_16x16x32_bf16(
                af, *(const bf16x8*)&sWo[nt*16 + l15][cs], acc[nt], 0, 0, 0);
    }

    float bsov[8], gov[8], bov[8];
    #pragma unroll
    for (int nt = 0; nt < 8; ++nt) {
        const int c = nt*16 + l15;
        bsov[nt] = bso[c]; gov[nt] = go[c]; bov[nt] = bo[c];
    }

    #pragma unroll
    for (int reg = 0; reg < 4; ++reg) {
        const int i = i0 + w*16 + quad*4 + reg;
        const float* prow = pair + ((size_t)i*N_ + j)*C_;
        float zz[8];
        float ssum = 0.f, ssq = 0.f;
        #pragma unroll
        for (int nt = 0; nt < 8; ++nt) {
            float zv = acc[nt][reg] + bsov[nt] + prow[nt*16 + l15];
            zz[nt] = zv; ssum += zv; ssq += zv*zv;
        }
        #pragma unroll
        for (int d = 1; d < 16; d <<= 1) {
            ssum += __shfl_xor(ssum, d);
            ssq  += __shfl_xor(ssq, d);
        }
        const float mm = ssum * (1.f/128.f);
        const float vv = ssq * (1.f/128.f) - mm*mm;
        const float rr = rsqrtf(vv + 1e-5f);
        float* orow = out + ((size_t)i*N_ + j)*C_;
        #pragma unroll
        for (int nt = 0; nt < 8; ++nt)
            orow[nt*16 + l15] = (zz[nt] - mm)*rr*gov[nt] + bov[nt];
    }
}

// ---------------------------------------------------------------------------
extern "C" void kernel_launch(void* const* d_in, const int* in_sizes, int n_in,
                              void* d_out, int out_size, void* d_ws, size_t ws_size,
                              hipStream_t stream)
{
    const float* pair    = (const float*)d_in[0];
    const float* g_left  = (const float*)d_in[1];
    const float* b_left  = (const float*)d_in[2];
    const float* g_right = (const float*)d_in[3];
    const float* b_right = (const float*)d_in[4];
    const float* g_out   = (const float*)d_in[5];
    const float* b_out   = (const float*)d_in[6];
    const float* W_l     = (const float*)d_in[7];
    const float* bias_l  = (const float*)d_in[8];
    const float* W_r     = (const float*)d_in[9];
    const float* bias_r  = (const float*)d_in[10];
    const float* W_g     = (const float*)d_in[11];
    const float* bias_g  = (const float*)d_in[12];
    const float* W_e     = (const float*)d_in[13];
    const float* bias_e  = (const float*)d_in[14];
    const float* W_o     = (const float*)d_in[15];
    const float* bias_o  = (const float*)d_in[16];

    const size_t PLANES128 = (size_t)128 * NN_;                       // elements
    const size_t NEED = PLANES128*2*2 + 65536*2 + 512*4 + 16384*2;    // bytes

    if (ws_size >= NEED) {
        // ---- single pass: all 128 h in one round (proven round 9) ----
        __bf16* leftC  = (__bf16*)d_out;
        __bf16* gateC  = leftC + PLANES128;
        __bf16* rightC = (__bf16*)d_ws;
        __bf16* outG   = rightC + PLANES128;
        char* prepBase = (char*)d_ws + PLANES128*2*2;
        __bf16* WtL = (__bf16*)prepBase;
        __bf16* WtE = WtL + 16384;
        __bf16* WtR = WtL + 32768;
        __bf16* WtG = WtL + 49152;
        float*  cL  = (float*)(WtL + 65536);
        float*  cR  = cL + 128;
        float*  sEw = cL + 256;
        float*  sGw = cL + 384;
        __bf16* WoS = (__bf16*)(cL + 512);

        prep<<<6, 128, 0, stream>>>(W_l, W_r, W_g, W_e, W_o,
                                    g_left, b_left, g_right, b_right,
                                    bias_l, bias_e, bias_r,
                                    WtL, WtE, WtR, WtG, cL, cR, sEw, sGw, WoS);
        p_proj<<<NN_/64, 256, 0, stream>>>(pair, WtL, WtE, WtR, WtG,
                                           cL, cR, sEw, sGw, bias_g,
                                           0, 4, leftC, rightC, gateC);
        t_right<<<128*21, 256, 0, stream>>>(rightC);
        k_einsum<<<128*9, 256, 0, stream>>>(leftC, rightC, gateC, outG);
        p_out<<<2304, 256, 0, stream>>>(outG, W_o, WoS, bias_o, pair,
                                        g_out, b_out, (float*)d_out);
    } else {
        // ---- fallback: r8-proven two-pass layout (WoS disabled: its home
        // in d_out would race with p_out's own output writes) ----
        __bf16* outG   = (__bf16*)d_ws;
        __bf16* leftC  = (__bf16*)d_out;
        __bf16* rightC = leftC + (size_t)64*NN_;
        __bf16* gateC  = leftC + (size_t)128*NN_;

        char* prepBase = (char*)d_out + ((size_t)60 << 20);
        __bf16* WtL = (__bf16*)prepBase;
        __bf16* WtE = WtL + 16384;
        __bf16* WtR = WtL + 32768;
        __bf16* WtG = WtL + 49152;
        float*  cL  = (float*)(WtL + 65536);
        float*  cR  = cL + 128;
        float*  sEw = cL + 256;
        float*  sGw = cL + 384;
        __bf16* WoS = (__bf16*)(cL + 512);   // written by prep, unused below

        prep<<<6, 128, 0, stream>>>(W_l, W_r, W_g, W_e, W_o,
                                    g_left, b_left, g_right, b_right,
                                    bias_l, bias_e, bias_r,
                                    WtL, WtE, WtR, WtG, cL, cR, sEw, sGw, WoS);

        for (int h0 = 0; h0 < 128; h0 += 64) {
            p_proj<<<NN_/64, 256, 0, stream>>>(pair, WtL, WtE, WtR, WtG,
                                               cL, cR, sEw, sGw, bias_g,
                                               h0, 2, leftC, rightC, gateC);
            t_right<<<64*21, 256, 0, stream>>>(rightC);
            k_einsum<<<64*9, 256, 0, stream>>>(leftC, rightC, gateC,
                                               outG + (size_t)h0*NN_);
        }
        p_out<<<2304, 256, 0, stream>>>(outG, W_o, (const __bf16*)nullptr,
                                        bias_o, pair,
                                        g_out, b_out, (float*)d_out);
    }
}